// Round 7
// baseline (329.784 us; speedup 1.0000x reference)
//
#include <hip/hip_runtime.h>

#define BATCH  16
#define NPRED  25200
#define NCLS   80
#define CDIM   85
#define TOPK   4096
#define NBUCK  4096
#define MAXDET 1000
#define CONF_T 0.25f
#define IOU_T  0.45f
#define MAXWH  7680.0f
#define ORD_BASE 0xBE800000u   // ord(0.25f); valid score s>0.25 <=> ord > ORD_BASE

typedef unsigned long long u64;
typedef unsigned int u32;
typedef unsigned short u16;
typedef unsigned char u8;

__device__ __forceinline__ u64 umax64(u64 a, u64 b) { return a > b ? a : b; }
__device__ __forceinline__ u64 umin64(u64 a, u64 b) { return a < b ? a : b; }

__device__ __forceinline__ void cx_u64(u64* a, int i, int p, bool desc) {
    u64 x = a[i], y = a[p];
    if (desc ? (x < y) : (x > y)) { a[i] = y; a[p] = x; }
}

// ---- bitonic stages k=kstart..4096 over 4096 elems, 1024 threads × 4 regs ----
// (kstart=2048 merges four alternating-direction 1024-runs into desc order)

__device__ void hybrid_sort4096_desc_ks(u64 r[4], u64* a, int kstart) {
    const int tid = threadIdx.x;
    for (int k = kstart; k <= 4096; k <<= 1) {
        if (k >= 512) {                      // LDS stages: j = min(k/2,2048) .. 256
            int jmax = (k >> 1) > 2048 ? 2048 : (k >> 1);
#pragma unroll
            for (int e = 0; e < 4; ++e) a[4 * tid + e] = r[e];
            __syncthreads();
            for (int j = jmax; j >= 256; j >>= 1) {
#pragma unroll
                for (int t2 = 0; t2 < 2; ++t2) {
                    int q = (t2 << 10) | tid;
                    int i = ((q & ~(j - 1)) << 1) | (q & (j - 1));
                    cx_u64(a, i, i | j, (i & k) == 0);
                }
                __syncthreads();
            }
#pragma unroll
            for (int e = 0; e < 4; ++e) r[e] = a[4 * tid + e];
            __syncthreads();
        }
        {                                    // shuffle stages: j = min(k/2,128) .. 4
            int jstart = (k >> 1) > 128 ? 128 : (k >> 1);
            bool desc = (((4 * tid) & k) == 0);
            for (int j = jstart; j >= 4; j >>= 1) {
                int m = j >> 2;
                bool take_max = (((tid & m) == 0) == desc);
#pragma unroll
                for (int e = 0; e < 4; ++e) {
                    u64 v = __shfl_xor(r[e], m, 64);
                    r[e] = take_max ? umax64(r[e], v) : umin64(r[e], v);
                }
            }
        }
        if (k >= 4) {                        // j=2
            bool desc = (((4 * tid) & k) == 0);
            u64 x0 = r[0], x2 = r[2];
            r[0] = desc ? umax64(x0, x2) : umin64(x0, x2);
            r[2] = desc ? umin64(x0, x2) : umax64(x0, x2);
            u64 x1 = r[1], x3 = r[3];
            r[1] = desc ? umax64(x1, x3) : umin64(x1, x3);
            r[3] = desc ? umin64(x1, x3) : umax64(x1, x3);
        }
        {                                    // j=1
            bool d01 = (((4 * tid + 0) & k) == 0);
            bool d23 = (((4 * tid + 2) & k) == 0);
            u64 x0 = r[0], x1 = r[1];
            r[0] = d01 ? umax64(x0, x1) : umin64(x0, x1);
            r[1] = d01 ? umin64(x0, x1) : umax64(x0, x1);
            u64 x2 = r[2], x3 = r[3];
            r[2] = d23 ? umax64(x2, x3) : umin64(x2, x3);
            r[3] = d23 ? umin64(x2, x3) : umax64(x2, x3);
        }
    }
}

// ---- full sort of a 1024-elem group arena, run by a 256-thread group (gtid 0..255)
// ---- inside a 1024-thread block; barrier pattern uniform across the 4 groups.

__device__ void group_sort1024_dir(u64 r[4], u64* a, int gtid, bool fdesc) {
    for (int k = 2; k <= 1024; k <<= 1) {
        if (k >= 512) {                      // LDS stages: j = k/2 .. 256
            int jmax = (k >> 1) > 512 ? 512 : (k >> 1);
#pragma unroll
            for (int e = 0; e < 4; ++e) a[4 * gtid + e] = r[e];
            __syncthreads();
            for (int j = jmax; j >= 256; j >>= 1) {
#pragma unroll
                for (int t2 = 0; t2 < 2; ++t2) {
                    int q = (t2 << 8) | gtid;
                    int i = ((q & ~(j - 1)) << 1) | (q & (j - 1));
                    cx_u64(a, i, i | j, ((i & k) == 0) == fdesc);
                }
                __syncthreads();
            }
#pragma unroll
            for (int e = 0; e < 4; ++e) r[e] = a[4 * gtid + e];
            __syncthreads();
        }
        {                                    // shuffle stages: j = min(k/2,128) .. 4
            int jstart = (k >> 1) > 128 ? 128 : (k >> 1);
            bool desc = ((((4 * gtid) & k) == 0) == fdesc);
            for (int j = jstart; j >= 4; j >>= 1) {
                int m = j >> 2;
                bool take_max = (((gtid & m) == 0) == desc);
#pragma unroll
                for (int e = 0; e < 4; ++e) {
                    u64 v = __shfl_xor(r[e], m, 64);
                    r[e] = take_max ? umax64(r[e], v) : umin64(r[e], v);
                }
            }
        }
        if (k >= 4) {                        // j=2
            bool desc = ((((4 * gtid) & k) == 0) == fdesc);
            u64 x0 = r[0], x2 = r[2];
            r[0] = desc ? umax64(x0, x2) : umin64(x0, x2);
            r[2] = desc ? umin64(x0, x2) : umax64(x0, x2);
            u64 x1 = r[1], x3 = r[3];
            r[1] = desc ? umax64(x1, x3) : umin64(x1, x3);
            r[3] = desc ? umin64(x1, x3) : umax64(x1, x3);
        }
        {                                    // j=1
            bool d01 = ((((4 * gtid + 0) & k) == 0) == fdesc);
            bool d23 = ((((4 * gtid + 2) & k) == 0) == fdesc);
            u64 x0 = r[0], x1 = r[1];
            r[0] = d01 ? umax64(x0, x1) : umin64(x0, x1);
            r[1] = d01 ? umin64(x0, x1) : umax64(x0, x1);
            u64 x2 = r[2], x3 = r[3];
            r[2] = d23 ? umax64(x2, x3) : umin64(x2, x3);
            r[3] = d23 ? umin64(x2, x3) : umax64(x2, x3);
        }
    }
}

// full desc sort of 256 u64 held in wave 0 (4 regs/lane), zero barriers
__device__ void wave_sort256_desc(u64 r[4]) {
    const int lane = threadIdx.x & 63;
    for (int k = 2; k <= 256; k <<= 1) {
        int jstart = (k >> 1) > 128 ? 128 : (k >> 1);
        bool desc = (((4 * lane) & k) == 0);
        for (int j = jstart; j >= 4; j >>= 1) {
            int m = j >> 2;
            bool take_max = (((lane & m) == 0) == desc);
#pragma unroll
            for (int e = 0; e < 4; ++e) {
                u64 v = __shfl_xor(r[e], m, 64);
                r[e] = take_max ? umax64(r[e], v) : umin64(r[e], v);
            }
        }
        if (k >= 4) {
            u64 x0 = r[0], x2 = r[2];
            r[0] = desc ? umax64(x0, x2) : umin64(x0, x2);
            r[2] = desc ? umin64(x0, x2) : umax64(x0, x2);
            u64 x1 = r[1], x3 = r[3];
            r[1] = desc ? umax64(x1, x3) : umin64(x1, x3);
            r[3] = desc ? umin64(x1, x3) : umax64(x1, x3);
        }
        {
            bool d01 = (((4 * lane + 0) & k) == 0);
            bool d23 = (((4 * lane + 2) & k) == 0);
            u64 x0 = r[0], x1 = r[1];
            r[0] = d01 ? umax64(x0, x1) : umin64(x0, x1);
            r[1] = d01 ? umin64(x0, x1) : umax64(x0, x1);
            u64 x2 = r[2], x3 = r[3];
            r[2] = d23 ? umax64(x2, x3) : umin64(x2, x3);
            r[3] = d23 ? umin64(x2, x3) : umax64(x2, x3);
        }
    }
}

// ---------------- K1: score / argmax / key ----------------
// key = ord(score)<<32 | (32767-n)<<7 | cls   (desc sort == stable argsort(-s))

__global__ __launch_bounds__(256) void k1_score(const float* __restrict__ pred,
                                                u64* __restrict__ keys) {
    const int lane = threadIdx.x & 63;
    const int l16 = lane & 15;
    const long long gw = (long long)blockIdx.x * 4 + (threadIdx.x >> 6);
    const long long rowIdx = gw * 4 + (lane >> 4);       // global row in [0, BATCH*NPRED)
    const int b = (int)(rowIdx / NPRED);
    const int n = (int)(rowIdx - (long long)b * NPRED);
    const float* row = pred + rowIdx * CDIM;
    float obj = row[4];
    u64 m = 0ull;
#pragma unroll
    for (int k = 0; k < 5; ++k) {
        int c = l16 + 16 * k;                            // covers 0..79
        float v = row[5 + c] * obj;                      // reference order: product then max
        u64 mk = ((u64)(__float_as_uint(v) | 0x80000000u) << 32) | (u64)(u32)(NCLS - 1 - c);
        if (mk > m) m = mk;                              // (79-c) low bits: ties pick smaller c
    }
#pragma unroll
    for (int o = 8; o > 0; o >>= 1) {
        u64 other = __shfl_xor(m, o, 64);                // reduce within 16-lane group
        if (other > m) m = other;
    }
    if (l16 == 0) {
        float best = __uint_as_float((u32)(m >> 32) & 0x7FFFFFFFu);
        int cls = (NCLS - 1) - (int)(m & 0x7Fu);
        float s = (best > CONF_T) ? best : -1.0f;
        u32 u = __float_as_uint(s);
        u32 ord = (u & 0x80000000u) ? ~u : (u | 0x80000000u);
        keys[rowIdx] = ((u64)ord << 32) | ((u64)(u32)(32767 - n) << 7) | (u64)(u32)cls;
    }
}

// ---------------- K2: hist + threshold + compact + full sort -> topSorted ----
// One 1024-thread block per batch. Sub-sorts of the four 1024-runs execute as
// 4 concurrent 256-thread groups (alternating direction), then k=2048/4096 merge.
// Also zeroes keep[] and done[] for this batch.

__global__ __launch_bounds__(1024) void k2_sel(const u64* __restrict__ keys,
                                               u64* __restrict__ topSorted,
                                               u8* __restrict__ keep,
                                               u32* __restrict__ done) {
    __shared__ u64 smem[4096];          // 32 KB compact/sort arena
    __shared__ u64 side[1024];          // bucket-T members
    __shared__ u32 hist[4096];          // 16 KB histogram
    __shared__ u32 wsum[16];
    __shared__ int sh_T, sh_C1, sh_R, c1pos, sidepos;
    const int b = blockIdx.x;
    const int tid = threadIdx.x;
    const int lane = tid & 63;
    const int wid = tid >> 6;
    const u64 lanelt = (1ull << lane) - 1ull;

    // --- zero LDS + keep + done ---
#pragma unroll
    for (int e = 0; e < 4; ++e) { smem[4 * tid + e] = 0ull; hist[4 * tid + e] = 0u; }
    side[tid] = 0ull;
    ((u32*)keep)[b * 1024 + tid] = 0u;                   // keep[b*4096 .. +4096) = 0
    if (tid == 0) done[b] = 0u;
    __syncthreads();

    // --- histogram over keys (in-LDS) ---
    const u64* kb = keys + (long long)b * NPRED;
    for (int it = 0; it < (NPRED + 1023) / 1024; ++it) {
        int n = it * 1024 + tid;
        if (n < NPRED) {
            u32 hi = (u32)(kb[n] >> 32);
            if (hi > ORD_BASE) atomicAdd(&hist[(hi - ORD_BASE - 1u) >> 12], 1u);
        }
    }
    __syncthreads();

    // --- threshold scan (descending order over buckets) ---
    u32 h[4];
    u32 tsum = 0;
#pragma unroll
    for (int e = 0; e < 4; ++e) {
        h[e] = hist[NBUCK - 1 - (4 * tid + e)];
        tsum += h[e];
    }
    u32 inc = tsum;
    for (int o = 1; o < 64; o <<= 1) {
        u32 v = __shfl_up(inc, o, 64);
        if (lane >= o) inc += v;
    }
    if (lane == 63) wsum[wid] = inc;
    __syncthreads();
    if (tid == 0) {
        u32 run = 0;
        for (int i = 0; i < 16; ++i) { u32 t = wsum[i]; wsum[i] = run; run += t; }
        sh_T = -1; sh_C1 = (int)run; sh_R = 0;           // defaults: < 4096 valid total
        c1pos = 0; sidepos = 0;
    }
    __syncthreads();
    {
        u32 cum = wsum[wid] + (inc - tsum);              // exclusive prefix before this thread
#pragma unroll
        for (int e = 0; e < 4; ++e) {
            if (h[e] > 0 && cum < (u32)TOPK && cum + h[e] >= (u32)TOPK) {
                sh_T = NBUCK - 1 - (4 * tid + e);        // unique crossing
                sh_C1 = (int)cum;
                sh_R = TOPK - (int)cum;
            }
            cum += h[e];
        }
    }
    __syncthreads();
    const int T = sh_T, C1 = sh_C1, R = sh_R;

    // --- compact (ballot-aggregated slot allocation) ---
    for (int it = 0; it < (NPRED + 1023) / 1024; ++it) {
        int n = it * 1024 + tid;
        bool act = n < NPRED;
        u64 key = act ? kb[n] : 0ull;
        u32 hi = (u32)(key >> 32);
        bool v = act && (hi > ORD_BASE);
        int bt = v ? (int)((hi - ORD_BASE - 1u) >> 12) : -1;
        bool t1 = v && (bt > T);
        bool t2 = v && (bt == T);
        u64 m1 = __ballot(t1), m2 = __ballot(t2);
        int b1 = 0, b2 = 0;
        if (lane == 0) {
            if (m1) b1 = atomicAdd(&c1pos, (int)__popcll(m1));
            if (m2) b2 = atomicAdd(&sidepos, (int)__popcll(m2));
        }
        b1 = __shfl(b1, 0, 64);
        b2 = __shfl(b2, 0, 64);
        if (t1) smem[b1 + __popcll(m1 & lanelt)] = key;
        if (t2) { int s2 = b2 + __popcll(m2 & lanelt); if (s2 < 1024) side[s2] = key; }
    }
    __syncthreads();

    // --- select R largest from bucket T ---
    if (R > 0) {
        int cntT = sidepos;
        if (cntT <= 256) {
            if (wid == 0) {                              // single-wave in-register sort
                u64 r[4];
#pragma unroll
                for (int e = 0; e < 4; ++e) r[e] = side[4 * lane + e];
                wave_sort256_desc(r);
#pragma unroll
                for (int e = 0; e < 4; ++e) side[4 * lane + e] = r[e];
            }
        } else {                                         // rare fallback: block bitonic 1024
            for (int k = 2; k <= 1024; k <<= 1) {
                for (int j = k >> 1; j >= 1; j >>= 1) {
                    if (tid < 512) {
                        int q = tid;
                        int i = ((q & ~(j - 1)) << 1) | (q & (j - 1));
                        cx_u64(side, i, i | j, (i & k) == 0);
                    }
                    __syncthreads();
                }
            }
        }
        __syncthreads();
        if (tid < R) smem[C1 + tid] = side[tid];         // R <= cntT <= 1024
    }
    __syncthreads();

    // --- 4 concurrent group sorts (desc,asc,desc,asc) + k=2048/4096 merge ---
    {
        const int g = tid >> 8;
        const int gtid = tid & 255;
        u64* ga = smem + (g << 10);
        u64 r[4];
#pragma unroll
        for (int e = 0; e < 4; ++e) r[e] = ga[4 * gtid + e];
        group_sort1024_dir(r, ga, gtid, (g & 1) == 0);
        // element 4*tid+e (global) == g*1024 + 4*gtid+e: registers flow into merge
        hybrid_sort4096_desc_ks(r, smem, 2048);
#pragma unroll
        for (int e = 0; e < 4; ++e) topSorted[(long long)b * TOPK + 4 * tid + e] = r[e];
    }
}

// ---------------- K3: per-(batch,class) gather + register NMS, one wave per block ----
// Last block of each batch (device-scope election) runs the output phase inline.

__global__ __launch_bounds__(64) void k3_nms(const float* __restrict__ pred,
                                             const u64* __restrict__ topSorted,
                                             u8* __restrict__ keep,
                                             u32* __restrict__ done,
                                             float* __restrict__ out) {
    const int b = blockIdx.x;
    const int c = blockIdx.y;
    const int lane = threadIdx.x;
    __shared__ u32 list[4096];           // (rank<<15)|n  for this class, rank-ascending
    __shared__ float4 sbox[1024];        // generic-path staging
    __shared__ u8 suppb[4096];           // generic-path suppression flags
    __shared__ u64 words[64];            // output-phase bitmap
    __shared__ int wpre[64];
    const u64* tb = topSorted + (long long)b * TOPK;
    const u64 lanelt = (1ull << lane) - 1ull;

    u32 pos = 0;
    for (int it = 0; it < 64; ++it) {
        u64 key = tb[it * 64 + lane];
        u32 hi = (u32)(key >> 32);
        bool mine = (hi > 0x80000000u) && ((int)(key & 0x7Fu) == c);
        u64 m = __ballot(mine);
        if (mine)
            list[pos + __popcll(m & lanelt)] =
                ((u32)(it * 64 + lane) << 15) | (32767u - (u32)((key >> 7) & 0x7FFFu));
        pos += (u32)__popcll(m);
    }
    const int n = (int)pos;
    u8* kb = keep + b * TOPK;
    const float off = (float)c * MAXWH;

    if (n > 0 && n <= 128) {
        u32 r0 = 0, r1 = 0;
        float4 b0 = make_float4(0.0f, 0.0f, 0.0f, 0.0f);
        float4 b1 = make_float4(0.0f, 0.0f, 0.0f, 0.0f);
        if (lane < n) {                  // box build: default contract, same expr as before
            u32 e = list[lane];
            r0 = e >> 15;
            const float* row = pred + ((long long)b * NPRED + (int)(e & 0x7FFFu)) * CDIM;
            float x = row[0], y = row[1], w = row[2], hh = row[3];
            b0.x = (x - w * 0.5f) + off;
            b0.y = (y - hh * 0.5f) + off;
            b0.z = (x + w * 0.5f) + off;
            b0.w = (y + hh * 0.5f) + off;
        }
        if (64 + lane < n) {
            u32 e = list[64 + lane];
            r1 = e >> 15;
            const float* row = pred + ((long long)b * NPRED + (int)(e & 0x7FFFu)) * CDIM;
            float x = row[0], y = row[1], w = row[2], hh = row[3];
            b1.x = (x - w * 0.5f) + off;
            b1.y = (y - hh * 0.5f) + off;
            b1.z = (x + w * 0.5f) + off;
            b1.w = (y + hh * 0.5f) + off;
        }
        {
#pragma clang fp contract(off)
            float a20 = (b0.z - b0.x) * (b0.w - b0.y);
            float a21 = (b1.z - b1.x) * (b1.w - b1.y);
            u64 rem0 = (n >= 64) ? ~0ull : ((1ull << n) - 1ull);
            u64 rem1 = (n > 64) ? ((n >= 128) ? ~0ull : ((1ull << (n - 64)) - 1ull)) : 0ull;
            u64 keep0 = 0ull, keep1 = 0ull;
            const bool two = (n > 64);
            while (rem0) {               // process slot-0 entries in ascending rank
                int ii = __builtin_ctzll(rem0);
                rem0 &= ~(1ull << ii);
                keep0 |= 1ull << ii;
                float bix = __shfl(b0.x, ii, 64);
                float biy = __shfl(b0.y, ii, 64);
                float biz = __shfl(b0.z, ii, 64);
                float biw = __shfl(b0.w, ii, 64);
                float a1  = __shfl(a20, ii, 64);
                {
                    float ltx = fmaxf(bix, b0.x), lty = fmaxf(biy, b0.y);
                    float rbx = fminf(biz, b0.z), rby = fminf(biw, b0.w);
                    float ww = fmaxf(rbx - ltx, 0.0f), hh = fmaxf(rby - lty, 0.0f);
                    float inter = ww * hh;
                    float iou = inter / (((a1 + a20) - inter) + 1e-7f);
                    bool k0 = (iou > IOU_T) && (lane > ii);
                    rem0 &= ~__ballot(k0);
                }
                if (two) {               // slot-1 entries are all later than ii
                    float ltx = fmaxf(bix, b1.x), lty = fmaxf(biy, b1.y);
                    float rbx = fminf(biz, b1.z), rby = fminf(biw, b1.w);
                    float ww = fmaxf(rbx - ltx, 0.0f), hh = fmaxf(rby - lty, 0.0f);
                    float inter = ww * hh;
                    float iou = inter / (((a1 + a21) - inter) + 1e-7f);
                    bool k1 = (iou > IOU_T);
                    rem1 &= ~__ballot(k1);
                }
            }
            while (rem1) {               // then slot-1 entries
                int ii = __builtin_ctzll(rem1);
                rem1 &= ~(1ull << ii);
                keep1 |= 1ull << ii;
                float bix = __shfl(b1.x, ii, 64);
                float biy = __shfl(b1.y, ii, 64);
                float biz = __shfl(b1.z, ii, 64);
                float biw = __shfl(b1.w, ii, 64);
                float a1  = __shfl(a21, ii, 64);
                float ltx = fmaxf(bix, b1.x), lty = fmaxf(biy, b1.y);
                float rbx = fminf(biz, b1.z), rby = fminf(biw, b1.w);
                float ww = fmaxf(rbx - ltx, 0.0f), hh = fmaxf(rby - lty, 0.0f);
                float inter = ww * hh;
                float iou = inter / (((a1 + a21) - inter) + 1e-7f);
                bool k1 = (iou > IOU_T) && (lane > ii);
                rem1 &= ~__ballot(k1);
            }
            if ((keep0 >> lane) & 1ull) kb[r0] = 1;
            if ((keep1 >> lane) & 1ull) kb[r1] = 1;
        }
    } else if (n > 128) {                // rare generic path
        for (int j = lane; j < 1024; j += 64) {
            if (j < n) {
                u32 e = list[j];
                const float* row = pred + ((long long)b * NPRED + (int)(e & 0x7FFFu)) * CDIM;
                float x = row[0], y = row[1], w = row[2], hh = row[3];
                float4 o;
                o.x = (x - w * 0.5f) + off;
                o.y = (y - hh * 0.5f) + off;
                o.z = (x + w * 0.5f) + off;
                o.w = (y + hh * 0.5f) + off;
                sbox[j] = o;
            }
        }
        for (int j = lane; j < n; j += 64) suppb[j] = 0;
        __syncthreads();
        volatile u8* supp = suppb;
        {
#pragma clang fp contract(off)
            for (int ii = 0; ii < n; ++ii) {
                if (supp[ii]) continue;  // wave-uniform (single-wave block)
                u32 ei = list[ii];
                int ri = (int)(ei >> 15);
                if (lane == 0) kb[ri] = 1;
                float4 bi;
                if (ii < 1024) bi = sbox[ii];
                else {
                    const float* row = pred + ((long long)b * NPRED + (int)(ei & 0x7FFFu)) * CDIM;
                    float x = row[0], y = row[1], w = row[2], hh = row[3];
                    bi.x = (x - w * 0.5f) + off;
                    bi.y = (y - hh * 0.5f) + off;
                    bi.z = (x + w * 0.5f) + off;
                    bi.w = (y + hh * 0.5f) + off;
                }
                float a1 = (bi.z - bi.x) * (bi.w - bi.y);
                for (int jj = ii + 1 + lane; jj < n; jj += 64) {
                    float4 bj;
                    if (jj < 1024) bj = sbox[jj];
                    else {
                        u32 ej = list[jj];
                        const float* row = pred + ((long long)b * NPRED + (int)(ej & 0x7FFFu)) * CDIM;
                        float x = row[0], y = row[1], w = row[2], hh = row[3];
                        bj.x = (x - w * 0.5f) + off;
                        bj.y = (y - hh * 0.5f) + off;
                        bj.z = (x + w * 0.5f) + off;
                        bj.w = (y + hh * 0.5f) + off;
                    }
                    float ltx = fmaxf(bi.x, bj.x), lty = fmaxf(bi.y, bj.y);
                    float rbx = fminf(bi.z, bj.z), rby = fminf(bi.w, bj.w);
                    float ww = fmaxf(rbx - ltx, 0.0f), hh = fmaxf(rby - lty, 0.0f);
                    float inter = ww * hh;
                    float a2 = (bj.z - bj.x) * (bj.w - bj.y);
                    float iou = inter / (((a1 + a2) - inter) + 1e-7f);
                    if (iou > IOU_T) supp[jj] = 1;
                }
                __syncthreads();         // single-wave: orders LDS supp writes
            }
        }
    }

    // ---- completion protocol: last (b,c) block for this batch emits output ----
    __threadfence();                     // make keep[] writes device-visible
    u32 prev = 0;
    if (lane == 0) prev = atomicAdd(&done[b], 1u);
    prev = __shfl(prev, 0, 64);
    if (prev == NCLS - 1) {
        __threadfence();                 // acquire: see all blocks' keep[] writes
        float* outb = out + (long long)b * MAXDET * 6;
        float4 z4 = make_float4(0.0f, 0.0f, 0.0f, 0.0f);
        float4* ob4 = (float4*)outb;     // MAXDET*6 floats = 1500 float4, 16B-aligned
        for (int i = lane; i < (MAXDET * 6) / 4; i += 64) ob4[i] = z4;   // d_out poisoned
        {
            u64 w = 0ull;
            const u64* k8 = (const u64*)(kb + lane * 64);
#pragma unroll
            for (int q = 0; q < 8; ++q) {
                u64 v = k8[q];
#pragma unroll
                for (int bb = 0; bb < 8; ++bb)
                    if ((v >> (8 * bb)) & 0xFFull) w |= 1ull << (q * 8 + bb);
            }
            words[lane] = w;
        }
        __syncthreads();
        if (lane == 0) {
            int run = 0;
            for (int t = 0; t < 64; ++t) { wpre[t] = run; run += __popcll(words[t]); }
        }
        __syncthreads();
        for (int r = lane; r < TOPK; r += 64) {
            int wd = r >> 6;
            u64 wv = words[wd];
            if ((wv >> (r & 63)) & 1ull) {
                int p = wpre[wd] + __popcll(wv & ((1ull << (r & 63)) - 1ull));
                if (p < MAXDET) {
                    u64 key = tb[r];
                    u32 hi = (u32)(key >> 32);
                    int nn = 32767 - (int)((key >> 7) & 0x7FFFu);
                    const float* row = pred + ((long long)b * NPRED + nn) * CDIM;
                    float x = row[0], y = row[1], w2 = row[2], hh = row[3];
                    float* o = outb + p * 6;
                    o[0] = x - w2 * 0.5f;
                    o[1] = y - hh * 0.5f;
                    o[2] = x + w2 * 0.5f;
                    o[3] = y + hh * 0.5f;
                    o[4] = __uint_as_float(hi & 0x7FFFFFFFu);   // score
                    o[5] = (float)(key & 0x7Fu);                // class (as float)
                }
            }
        }
    }
}

// ---------------- launch ----------------

extern "C" void kernel_launch(void* const* d_in, const int* in_sizes, int n_in,
                              void* d_out, int out_size, void* d_ws, size_t ws_size,
                              hipStream_t stream) {
    const float* pred = (const float*)d_in[0];
    float* out = (float*)d_out;

    char* ws = (char*)d_ws;
    u64* keys      = (u64*)ws;                            // 16*25200*8 = 3,225,600 B
    u64* topSorted = (u64*)(ws + 3225600);                // 16*4096*8  =   524,288 B
    u8*  keep      = (u8*)(ws + 3749888);                 //    65,536 B  [zeroed in k2]
    u32* done      = (u32*)(ws + 3815424);                //        64 B  [zeroed in k2]

    hipLaunchKernelGGL(k1_score, dim3(BATCH * NPRED / 16), dim3(256), 0, stream,
                       pred, keys);
    hipLaunchKernelGGL(k2_sel, dim3(BATCH), dim3(1024), 0, stream,
                       keys, topSorted, keep, done);
    hipLaunchKernelGGL(k3_nms, dim3(BATCH, NCLS), dim3(64), 0, stream,
                       pred, topSorted, keep, done, out);
}

// Round 8
// 273.455 us; speedup vs baseline: 1.2060x; 1.2060x over previous
//
#include <hip/hip_runtime.h>

#define BATCH  16
#define NPRED  25200
#define NCLS   80
#define CDIM   85
#define TOPK   4096
#define NBUCK  4096
#define MAXDET 1000
#define CONF_T 0.25f
#define IOU_T  0.45f
#define MAXWH  7680.0f
#define ORD_BASE 0xBE800000u   // ord(0.25f); valid score s>0.25 <=> ord > ORD_BASE

typedef unsigned long long u64;
typedef unsigned int u32;
typedef unsigned short u16;
typedef unsigned char u8;

__device__ __forceinline__ u64 umax64(u64 a, u64 b) { return a > b ? a : b; }
__device__ __forceinline__ u64 umin64(u64 a, u64 b) { return a < b ? a : b; }

__device__ __forceinline__ void cx_u64(u64* a, int i, int p, bool desc) {
    u64 x = a[i], y = a[p];
    if (desc ? (x < y) : (x > y)) { a[i] = y; a[p] = x; }
}

// box build under DEFAULT contract (lexically outside any fp-contract pragma):
// bit-identical to the verified staging-path codegen.
__device__ __forceinline__ float4 build_box(const float* __restrict__ row, float off) {
    float x = row[0], y = row[1], w = row[2], hh = row[3];
    float4 o;
    o.x = (x - w * 0.5f) + off;
    o.y = (y - hh * 0.5f) + off;
    o.z = (x + w * 0.5f) + off;
    o.w = (y + hh * 0.5f) + off;
    return o;
}

// ---- bitonic stages k=kstart..4096 over 4096 elems, 1024 threads × 4 regs ----
// (kstart=2 is a full desc sort; kstart=2048 merges four alternating 1024-runs)

__device__ void hybrid_sort4096_desc_ks(u64 r[4], u64* a, int kstart) {
    const int tid = threadIdx.x;
    for (int k = kstart; k <= 4096; k <<= 1) {
        if (k >= 512) {                      // LDS stages: j = min(k/2,2048) .. 256
            int jmax = (k >> 1) > 2048 ? 2048 : (k >> 1);
#pragma unroll
            for (int e = 0; e < 4; ++e) a[4 * tid + e] = r[e];
            __syncthreads();
            for (int j = jmax; j >= 256; j >>= 1) {
#pragma unroll
                for (int t2 = 0; t2 < 2; ++t2) {
                    int q = (t2 << 10) | tid;
                    int i = ((q & ~(j - 1)) << 1) | (q & (j - 1));
                    cx_u64(a, i, i | j, (i & k) == 0);
                }
                __syncthreads();
            }
#pragma unroll
            for (int e = 0; e < 4; ++e) r[e] = a[4 * tid + e];
            __syncthreads();
        }
        {                                    // shuffle stages: j = min(k/2,128) .. 4
            int jstart = (k >> 1) > 128 ? 128 : (k >> 1);
            bool desc = (((4 * tid) & k) == 0);
            for (int j = jstart; j >= 4; j >>= 1) {
                int m = j >> 2;
                bool take_max = (((tid & m) == 0) == desc);
#pragma unroll
                for (int e = 0; e < 4; ++e) {
                    u64 v = __shfl_xor(r[e], m, 64);
                    r[e] = take_max ? umax64(r[e], v) : umin64(r[e], v);
                }
            }
        }
        if (k >= 4) {                        // j=2
            bool desc = (((4 * tid) & k) == 0);
            u64 x0 = r[0], x2 = r[2];
            r[0] = desc ? umax64(x0, x2) : umin64(x0, x2);
            r[2] = desc ? umin64(x0, x2) : umax64(x0, x2);
            u64 x1 = r[1], x3 = r[3];
            r[1] = desc ? umax64(x1, x3) : umin64(x1, x3);
            r[3] = desc ? umin64(x1, x3) : umax64(x1, x3);
        }
        {                                    // j=1
            bool d01 = (((4 * tid + 0) & k) == 0);
            bool d23 = (((4 * tid + 2) & k) == 0);
            u64 x0 = r[0], x1 = r[1];
            r[0] = d01 ? umax64(x0, x1) : umin64(x0, x1);
            r[1] = d01 ? umin64(x0, x1) : umax64(x0, x1);
            u64 x2 = r[2], x3 = r[3];
            r[2] = d23 ? umax64(x2, x3) : umin64(x2, x3);
            r[3] = d23 ? umin64(x2, x3) : umax64(x2, x3);
        }
    }
}

// ---- full sort of 1024 elems, 256 threads × 4 regs, final direction fdesc ----

__device__ void hybrid_sort1024_dir(u64 r[4], u64* a, bool fdesc) {
    const int tid = threadIdx.x;             // 0..255
    for (int k = 2; k <= 1024; k <<= 1) {
        if (k >= 512) {                      // LDS stages: j = k/2 .. 256
            int jmax = (k >> 1) > 512 ? 512 : (k >> 1);
#pragma unroll
            for (int e = 0; e < 4; ++e) a[4 * tid + e] = r[e];
            __syncthreads();
            for (int j = jmax; j >= 256; j >>= 1) {
#pragma unroll
                for (int t2 = 0; t2 < 2; ++t2) {
                    int q = (t2 << 8) | tid;
                    int i = ((q & ~(j - 1)) << 1) | (q & (j - 1));
                    cx_u64(a, i, i | j, ((i & k) == 0) == fdesc);
                }
                __syncthreads();
            }
#pragma unroll
            for (int e = 0; e < 4; ++e) r[e] = a[4 * tid + e];
            __syncthreads();
        }
        {                                    // shuffle stages: j = min(k/2,128) .. 4
            int jstart = (k >> 1) > 128 ? 128 : (k >> 1);
            bool desc = ((((4 * tid) & k) == 0) == fdesc);
            for (int j = jstart; j >= 4; j >>= 1) {
                int m = j >> 2;
                bool take_max = (((tid & m) == 0) == desc);
#pragma unroll
                for (int e = 0; e < 4; ++e) {
                    u64 v = __shfl_xor(r[e], m, 64);
                    r[e] = take_max ? umax64(r[e], v) : umin64(r[e], v);
                }
            }
        }
        if (k >= 4) {                        // j=2
            bool desc = ((((4 * tid) & k) == 0) == fdesc);
            u64 x0 = r[0], x2 = r[2];
            r[0] = desc ? umax64(x0, x2) : umin64(x0, x2);
            r[2] = desc ? umin64(x0, x2) : umax64(x0, x2);
            u64 x1 = r[1], x3 = r[3];
            r[1] = desc ? umax64(x1, x3) : umin64(x1, x3);
            r[3] = desc ? umin64(x1, x3) : umax64(x1, x3);
        }
        {                                    // j=1
            bool d01 = ((((4 * tid + 0) & k) == 0) == fdesc);
            bool d23 = ((((4 * tid + 2) & k) == 0) == fdesc);
            u64 x0 = r[0], x1 = r[1];
            r[0] = d01 ? umax64(x0, x1) : umin64(x0, x1);
            r[1] = d01 ? umin64(x0, x1) : umax64(x0, x1);
            u64 x2 = r[2], x3 = r[3];
            r[2] = d23 ? umax64(x2, x3) : umin64(x2, x3);
            r[3] = d23 ? umin64(x2, x3) : umax64(x2, x3);
        }
    }
}

// full desc sort of 256 u64 held in wave 0 (4 regs/lane), zero barriers
__device__ void wave_sort256_desc(u64 r[4]) {
    const int lane = threadIdx.x & 63;
    for (int k = 2; k <= 256; k <<= 1) {
        int jstart = (k >> 1) > 128 ? 128 : (k >> 1);
        bool desc = (((4 * lane) & k) == 0);
        for (int j = jstart; j >= 4; j >>= 1) {
            int m = j >> 2;
            bool take_max = (((lane & m) == 0) == desc);
#pragma unroll
            for (int e = 0; e < 4; ++e) {
                u64 v = __shfl_xor(r[e], m, 64);
                r[e] = take_max ? umax64(r[e], v) : umin64(r[e], v);
            }
        }
        if (k >= 4) {
            u64 x0 = r[0], x2 = r[2];
            r[0] = desc ? umax64(x0, x2) : umin64(x0, x2);
            r[2] = desc ? umin64(x0, x2) : umax64(x0, x2);
            u64 x1 = r[1], x3 = r[3];
            r[1] = desc ? umax64(x1, x3) : umin64(x1, x3);
            r[3] = desc ? umin64(x1, x3) : umax64(x1, x3);
        }
        {
            bool d01 = (((4 * lane + 0) & k) == 0);
            bool d23 = (((4 * lane + 2) & k) == 0);
            u64 x0 = r[0], x1 = r[1];
            r[0] = d01 ? umax64(x0, x1) : umin64(x0, x1);
            r[1] = d01 ? umin64(x0, x1) : umax64(x0, x1);
            u64 x2 = r[2], x3 = r[3];
            r[2] = d23 ? umax64(x2, x3) : umin64(x2, x3);
            r[3] = d23 ? umin64(x2, x3) : umax64(x2, x3);
        }
    }
}

// ---------------- K1: score / argmax / key ----------------
// key = ord(score)<<32 | (32767-n)<<7 | cls   (desc sort == stable argsort(-s))

__global__ __launch_bounds__(256) void k1_score(const float* __restrict__ pred,
                                                u64* __restrict__ keys) {
    const int lane = threadIdx.x & 63;
    const int l16 = lane & 15;
    const long long gw = (long long)blockIdx.x * 4 + (threadIdx.x >> 6);
    const long long rowIdx = gw * 4 + (lane >> 4);       // global row in [0, BATCH*NPRED)
    const int b = (int)(rowIdx / NPRED);
    const int n = (int)(rowIdx - (long long)b * NPRED);
    const float* row = pred + rowIdx * CDIM;
    float obj = row[4];
    u64 m = 0ull;
#pragma unroll
    for (int k = 0; k < 5; ++k) {
        int c = l16 + 16 * k;                            // covers 0..79
        float v = row[5 + c] * obj;                      // reference order: product then max
        u64 mk = ((u64)(__float_as_uint(v) | 0x80000000u) << 32) | (u64)(u32)(NCLS - 1 - c);
        if (mk > m) m = mk;                              // (79-c) low bits: ties pick smaller c
    }
#pragma unroll
    for (int o = 8; o > 0; o >>= 1) {
        u64 other = __shfl_xor(m, o, 64);                // reduce within 16-lane group
        if (other > m) m = other;
    }
    if (l16 == 0) {
        float best = __uint_as_float((u32)(m >> 32) & 0x7FFFFFFFu);
        int cls = (NCLS - 1) - (int)(m & 0x7Fu);
        float s = (best > CONF_T) ? best : -1.0f;
        u32 u = __float_as_uint(s);
        u32 ord = (u & 0x80000000u) ? ~u : (u | 0x80000000u);
        keys[rowIdx] = ((u64)ord << 32) | ((u64)(u32)(32767 - n) << 7) | (u64)(u32)cls;
    }
}

// ---------------- K2a: in-LDS histogram + threshold + ballot compact -> topUn ----

__global__ __launch_bounds__(1024) void k2a(const u64* __restrict__ keys,
                                            u64* __restrict__ topUn,
                                            u8* __restrict__ keep) {
    __shared__ u64 smem[4096];          // 32 KB compact arena
    __shared__ u64 side[1024];          // bucket-T members
    __shared__ u32 hist[4096];          // 16 KB histogram
    __shared__ u32 wsum[16];
    __shared__ int sh_T, sh_C1, sh_R, c1pos, sidepos;
    const int b = blockIdx.x;
    const int tid = threadIdx.x;
    const int lane = tid & 63;
    const int wid = tid >> 6;
    const u64 lanelt = (1ull << lane) - 1ull;

    // --- zero LDS + keep ---
#pragma unroll
    for (int e = 0; e < 4; ++e) { smem[4 * tid + e] = 0ull; hist[4 * tid + e] = 0u; }
    side[tid] = 0ull;
    ((u32*)keep)[b * 1024 + tid] = 0u;                   // keep[b*4096 .. +4096) = 0
    __syncthreads();

    // --- histogram over keys (in-LDS) ---
    const u64* kb = keys + (long long)b * NPRED;
    for (int it = 0; it < (NPRED + 1023) / 1024; ++it) {
        int n = it * 1024 + tid;
        if (n < NPRED) {
            u32 hi = (u32)(kb[n] >> 32);
            if (hi > ORD_BASE) atomicAdd(&hist[(hi - ORD_BASE - 1u) >> 12], 1u);
        }
    }
    __syncthreads();

    // --- threshold scan (descending order over buckets) ---
    u32 h[4];
    u32 tsum = 0;
#pragma unroll
    for (int e = 0; e < 4; ++e) {
        h[e] = hist[NBUCK - 1 - (4 * tid + e)];
        tsum += h[e];
    }
    u32 inc = tsum;
    for (int o = 1; o < 64; o <<= 1) {
        u32 v = __shfl_up(inc, o, 64);
        if (lane >= o) inc += v;
    }
    if (lane == 63) wsum[wid] = inc;
    __syncthreads();
    if (tid == 0) {
        u32 run = 0;
        for (int i = 0; i < 16; ++i) { u32 t = wsum[i]; wsum[i] = run; run += t; }
        sh_T = -1; sh_C1 = (int)run; sh_R = 0;           // defaults: < 4096 valid total
        c1pos = 0; sidepos = 0;
    }
    __syncthreads();
    {
        u32 cum = wsum[wid] + (inc - tsum);              // exclusive prefix before this thread
#pragma unroll
        for (int e = 0; e < 4; ++e) {
            if (h[e] > 0 && cum < (u32)TOPK && cum + h[e] >= (u32)TOPK) {
                sh_T = NBUCK - 1 - (4 * tid + e);        // unique crossing
                sh_C1 = (int)cum;
                sh_R = TOPK - (int)cum;
            }
            cum += h[e];
        }
    }
    __syncthreads();
    const int T = sh_T, C1 = sh_C1, R = sh_R;

    // --- compact (ballot-aggregated slot allocation) ---
    for (int it = 0; it < (NPRED + 1023) / 1024; ++it) {
        int n = it * 1024 + tid;
        bool act = n < NPRED;
        u64 key = act ? kb[n] : 0ull;
        u32 hi = (u32)(key >> 32);
        bool v = act && (hi > ORD_BASE);
        int bt = v ? (int)((hi - ORD_BASE - 1u) >> 12) : -1;
        bool t1 = v && (bt > T);
        bool t2 = v && (bt == T);
        u64 m1 = __ballot(t1), m2 = __ballot(t2);
        int b1 = 0, b2 = 0;
        if (lane == 0) {
            if (m1) b1 = atomicAdd(&c1pos, (int)__popcll(m1));
            if (m2) b2 = atomicAdd(&sidepos, (int)__popcll(m2));
        }
        b1 = __shfl(b1, 0, 64);
        b2 = __shfl(b2, 0, 64);
        if (t1) smem[b1 + __popcll(m1 & lanelt)] = key;
        if (t2) { int s2 = b2 + __popcll(m2 & lanelt); if (s2 < 1024) side[s2] = key; }
    }
    __syncthreads();

    // --- select R largest from bucket T ---
    if (R > 0) {
        int cntT = sidepos;
        if (cntT <= 256) {
            if (wid == 0) {                              // single-wave in-register sort
                u64 r[4];
#pragma unroll
                for (int e = 0; e < 4; ++e) r[e] = side[4 * lane + e];
                wave_sort256_desc(r);
#pragma unroll
                for (int e = 0; e < 4; ++e) side[4 * lane + e] = r[e];
            }
        } else {                                         // rare fallback: block bitonic 1024
            for (int k = 2; k <= 1024; k <<= 1) {
                for (int j = k >> 1; j >= 1; j >>= 1) {
                    if (tid < 512) {
                        int q = tid;
                        int i = ((q & ~(j - 1)) << 1) | (q & (j - 1));
                        cx_u64(side, i, i | j, (i & k) == 0);
                    }
                    __syncthreads();
                }
            }
        }
        __syncthreads();
        if (tid < R) smem[C1 + tid] = side[tid];         // R <= cntT <= 1024
    }
    __syncthreads();

    // --- dump unsorted arena ---
    for (int i = tid; i < 4096; i += 1024) topUn[(long long)b * TOPK + i] = smem[i];
}

// ---------------- K2b: sort each 1024-run (alternating direction), 64 blocks ----

__global__ __launch_bounds__(256) void k2b(u64* __restrict__ topUn) {
    __shared__ u64 a[1024];
    const int tid = threadIdx.x;
    const int s = blockIdx.x & 3;                        // run index within batch
    const long long base = (long long)blockIdx.x * 1024;
    u64 r[4];
#pragma unroll
    for (int e = 0; e < 4; ++e) r[e] = topUn[base + 4 * tid + e];
    hybrid_sort1024_dir(r, a, (s & 1) == 0);             // desc, asc, desc, asc
#pragma unroll
    for (int e = 0; e < 4; ++e) topUn[base + 4 * tid + e] = r[e];
}

// ---------------- K2c: bitonic merge stages k=2048,4096 -> sorted top-4096 ----

__global__ __launch_bounds__(1024) void k2c(const u64* __restrict__ topUn,
                                            u64* __restrict__ topSorted) {
    __shared__ u64 a[4096];
    const int b = blockIdx.x;
    const int tid = threadIdx.x;
    u64 r[4];
#pragma unroll
    for (int e = 0; e < 4; ++e) r[e] = topUn[(long long)b * TOPK + 4 * tid + e];
    hybrid_sort4096_desc_ks(r, a, 2048);
#pragma unroll
    for (int e = 0; e < 4; ++e) topSorted[(long long)b * TOPK + 4 * tid + e] = r[e];
}

// ---------------- K3: per-(batch,class) gather + register NMS, one wave per block ----
// LDS cut to 20.5 KB (list + suppb only; boxes built on the fly via build_box)
// -> 8 blocks/CU resident for 2x latency hiding.

__global__ __launch_bounds__(64) void k3_nms(const float* __restrict__ pred,
                                             const u64* __restrict__ topSorted,
                                             u8* __restrict__ keep) {
    const int b = blockIdx.x;
    const int c = blockIdx.y;
    const int lane = threadIdx.x;
    __shared__ u32 list[4096];           // (rank<<15)|n  for this class, rank-ascending
    __shared__ u8 suppb[4096];           // generic-path suppression flags
    const u64* tb = topSorted + (long long)b * TOPK;
    const u64 lanelt = (1ull << lane) - 1ull;

    u32 pos = 0;
    for (int it = 0; it < 64; ++it) {
        u64 key = tb[it * 64 + lane];
        u32 hi = (u32)(key >> 32);
        bool mine = (hi > 0x80000000u) && ((int)(key & 0x7Fu) == c);
        u64 m = __ballot(mine);
        if (mine)
            list[pos + __popcll(m & lanelt)] =
                ((u32)(it * 64 + lane) << 15) | (32767u - (u32)((key >> 7) & 0x7FFFu));
        pos += (u32)__popcll(m);
    }
    const int n = (int)pos;
    if (n == 0) return;
    u8* kb = keep + b * TOPK;
    const float off = (float)c * MAXWH;

    if (n <= 128) {
        u32 r0 = 0, r1 = 0;
        float4 b0 = make_float4(0.0f, 0.0f, 0.0f, 0.0f);
        float4 b1 = make_float4(0.0f, 0.0f, 0.0f, 0.0f);
        if (lane < n) {                  // box build: default contract (helper)
            u32 e = list[lane];
            r0 = e >> 15;
            b0 = build_box(pred + ((long long)b * NPRED + (int)(e & 0x7FFFu)) * CDIM, off);
        }
        if (64 + lane < n) {
            u32 e = list[64 + lane];
            r1 = e >> 15;
            b1 = build_box(pred + ((long long)b * NPRED + (int)(e & 0x7FFFu)) * CDIM, off);
        }
        {
#pragma clang fp contract(off)
            float a20 = (b0.z - b0.x) * (b0.w - b0.y);
            float a21 = (b1.z - b1.x) * (b1.w - b1.y);
            u64 rem0 = (n >= 64) ? ~0ull : ((1ull << n) - 1ull);
            u64 rem1 = (n > 64) ? ((n >= 128) ? ~0ull : ((1ull << (n - 64)) - 1ull)) : 0ull;
            u64 keep0 = 0ull, keep1 = 0ull;
            const bool two = (n > 64);
            while (rem0) {               // process slot-0 entries in ascending rank
                int ii = __builtin_ctzll(rem0);
                rem0 &= ~(1ull << ii);
                keep0 |= 1ull << ii;
                float bix = __shfl(b0.x, ii, 64);
                float biy = __shfl(b0.y, ii, 64);
                float biz = __shfl(b0.z, ii, 64);
                float biw = __shfl(b0.w, ii, 64);
                float a1  = __shfl(a20, ii, 64);
                {
                    float ltx = fmaxf(bix, b0.x), lty = fmaxf(biy, b0.y);
                    float rbx = fminf(biz, b0.z), rby = fminf(biw, b0.w);
                    float ww = fmaxf(rbx - ltx, 0.0f), hh = fmaxf(rby - lty, 0.0f);
                    float inter = ww * hh;
                    float iou = inter / (((a1 + a20) - inter) + 1e-7f);
                    bool k0 = (iou > IOU_T) && (lane > ii);
                    rem0 &= ~__ballot(k0);
                }
                if (two) {               // slot-1 entries are all later than ii
                    float ltx = fmaxf(bix, b1.x), lty = fmaxf(biy, b1.y);
                    float rbx = fminf(biz, b1.z), rby = fminf(biw, b1.w);
                    float ww = fmaxf(rbx - ltx, 0.0f), hh = fmaxf(rby - lty, 0.0f);
                    float inter = ww * hh;
                    float iou = inter / (((a1 + a21) - inter) + 1e-7f);
                    bool k1 = (iou > IOU_T);
                    rem1 &= ~__ballot(k1);
                }
            }
            while (rem1) {               // then slot-1 entries
                int ii = __builtin_ctzll(rem1);
                rem1 &= ~(1ull << ii);
                keep1 |= 1ull << ii;
                float bix = __shfl(b1.x, ii, 64);
                float biy = __shfl(b1.y, ii, 64);
                float biz = __shfl(b1.z, ii, 64);
                float biw = __shfl(b1.w, ii, 64);
                float a1  = __shfl(a21, ii, 64);
                float ltx = fmaxf(bix, b1.x), lty = fmaxf(biy, b1.y);
                float rbx = fminf(biz, b1.z), rby = fminf(biw, b1.w);
                float ww = fmaxf(rbx - ltx, 0.0f), hh = fmaxf(rby - lty, 0.0f);
                float inter = ww * hh;
                float iou = inter / (((a1 + a21) - inter) + 1e-7f);
                bool k1 = (iou > IOU_T) && (lane > ii);
                rem1 &= ~__ballot(k1);
            }
            if ((keep0 >> lane) & 1ull) kb[r0] = 1;
            if ((keep1 >> lane) & 1ull) kb[r1] = 1;
        }
    } else {                             // rare generic path (n > 128): boxes rebuilt on use
        for (int j = lane; j < n; j += 64) suppb[j] = 0;
        __syncthreads();
        volatile u8* supp = suppb;
        {
#pragma clang fp contract(off)
            for (int ii = 0; ii < n; ++ii) {
                if (supp[ii]) continue;  // wave-uniform (single-wave block)
                u32 ei = list[ii];
                int ri = (int)(ei >> 15);
                if (lane == 0) kb[ri] = 1;
                float4 bi = build_box(pred + ((long long)b * NPRED + (int)(ei & 0x7FFFu)) * CDIM, off);
                float a1 = (bi.z - bi.x) * (bi.w - bi.y);
                for (int jj = ii + 1 + lane; jj < n; jj += 64) {
                    u32 ej = list[jj];
                    float4 bj = build_box(pred + ((long long)b * NPRED + (int)(ej & 0x7FFFu)) * CDIM, off);
                    float ltx = fmaxf(bi.x, bj.x), lty = fmaxf(bi.y, bj.y);
                    float rbx = fminf(bi.z, bj.z), rby = fminf(bi.w, bj.w);
                    float ww = fmaxf(rbx - ltx, 0.0f), hh = fmaxf(rby - lty, 0.0f);
                    float inter = ww * hh;
                    float a2 = (bj.z - bj.x) * (bj.w - bj.y);
                    float iou = inter / (((a1 + a2) - inter) + 1e-7f);
                    if (iou > IOU_T) supp[jj] = 1;
                }
                __syncthreads();         // single-wave: orders LDS supp writes
            }
        }
    }
}

// ---------------- K4: rank-order compaction + output ----------------

__global__ __launch_bounds__(256) void k4_out(const float* __restrict__ pred,
                                              const u64* __restrict__ topSorted,
                                              const u8* __restrict__ keep,
                                              float* __restrict__ out) {
    const int b = blockIdx.x;
    const int tid = threadIdx.x;
    __shared__ u64 words[64];
    __shared__ int wpre[64];
    float* outb = out + (long long)b * MAXDET * 6;
    for (int i = tid; i < MAXDET * 6; i += 256) outb[i] = 0.0f;   // d_out is poisoned
    const u8* kp = keep + b * 4096;
    if (tid < 64) {
        u64 w = 0ull;
        const u64* k8 = (const u64*)(kp + tid * 64);
#pragma unroll
        for (int q = 0; q < 8; ++q) {
            u64 v = k8[q];
#pragma unroll
            for (int bb = 0; bb < 8; ++bb)
                if ((v >> (8 * bb)) & 0xFFull) w |= 1ull << (q * 8 + bb);
        }
        words[tid] = w;
    }
    __syncthreads();
    if (tid == 0) {
        int run = 0;
        for (int t = 0; t < 64; ++t) { wpre[t] = run; run += __popcll(words[t]); }
    }
    __syncthreads();
    const u64* kb = topSorted + (long long)b * TOPK;
    for (int r = tid; r < 4096; r += 256) {
        int wd = r >> 6;
        if ((words[wd] >> (r & 63)) & 1ull) {
            int pos = wpre[wd] + __popcll(words[wd] & ((1ull << (r & 63)) - 1ull));
            if (pos < MAXDET) {
                u64 key = kb[r];
                u32 hi = (u32)(key >> 32);
                int n = 32767 - (int)((key >> 7) & 0x7FFFu);
                const float* row = pred + ((long long)b * NPRED + n) * CDIM;
                float x = row[0], y = row[1], w2 = row[2], h = row[3];
                float* o = outb + pos * 6;
                o[0] = x - w2 * 0.5f;
                o[1] = y - h * 0.5f;
                o[2] = x + w2 * 0.5f;
                o[3] = y + h * 0.5f;
                o[4] = __uint_as_float(hi & 0x7FFFFFFFu);   // score
                o[5] = (float)(key & 0x7Fu);                // class (as float)
            }
        }
    }
}

// ---------------- launch ----------------

extern "C" void kernel_launch(void* const* d_in, const int* in_sizes, int n_in,
                              void* d_out, int out_size, void* d_ws, size_t ws_size,
                              hipStream_t stream) {
    const float* pred = (const float*)d_in[0];
    float* out = (float*)d_out;

    char* ws = (char*)d_ws;
    u64* keys      = (u64*)ws;                            // 16*25200*8 = 3,225,600 B
    u64* topUn     = (u64*)(ws + 3225600);                // 16*4096*8  =   524,288 B
    u64* topSorted = (u64*)(ws + 3749888);                // 16*4096*8  =   524,288 B
    u8*  keep      = (u8*)(ws + 4274176);                 //    65,536 B  [zeroed in k2a]

    hipLaunchKernelGGL(k1_score, dim3(BATCH * NPRED / 16), dim3(256), 0, stream,
                       pred, keys);
    hipLaunchKernelGGL(k2a, dim3(BATCH), dim3(1024), 0, stream, keys, topUn, keep);
    hipLaunchKernelGGL(k2b, dim3(BATCH * 4), dim3(256), 0, stream, topUn);
    hipLaunchKernelGGL(k2c, dim3(BATCH), dim3(1024), 0, stream, topUn, topSorted);
    hipLaunchKernelGGL(k3_nms, dim3(BATCH, NCLS), dim3(64), 0, stream,
                       pred, topSorted, keep);
    hipLaunchKernelGGL(k4_out, dim3(BATCH), dim3(256), 0, stream, pred, topSorted, keep, out);
}